// Round 7
// baseline (218.730 us; speedup 1.0000x reference)
//
#include <hip/hip_runtime.h>
#include <hip/hip_bf16.h>

typedef __attribute__((ext_vector_type(8))) short bf16x8;
typedef __attribute__((ext_vector_type(4))) float f32x4;

#define NB 16
#define C 256
#define HH 56
#define WW 56
#define HW 3136
#define CHW 802816
#define NPIX 50176
#define PH 58
#define PW 58
#define KTOT 2304
#define PPI 3364      // 58*58 padded pixels per image
#define NPIXP 53824   // 16*3364 total padded pixels

#define GLL(g, l) __builtin_amdgcn_global_load_lds( \
    (const __attribute__((address_space(1))) void*)(g), \
    (__attribute__((address_space(3))) void*)(l), 16, 0, 0)

// ---- kernel 1 (merged): BN stats + weight prep + Tp border zero + csum zero ----
__global__ __launch_bounds__(1024) void prep_stats_kernel(const float* __restrict__ x,
                             const float* __restrict__ gamma, const float* __restrict__ cw,
                             double* __restrict__ stats, unsigned short* __restrict__ Wp,
                             unsigned short* __restrict__ Tp, float* __restrict__ csum) {
  int b = blockIdx.x, tid = threadIdx.x;
  if (b < 256) {
    int c = b;
    double s = 0.0, s2 = 0.0;
    const float* xc = x + (size_t)c * HW;
    for (int k = tid; k < NB * (HW / 4); k += 1024) {   // 12544 float4s
      int n = k / (HW / 4), i = k - n * (HW / 4);
      float4 v = *(const float4*)(xc + (size_t)n * CHW + i * 4);
      double a = v.x, bb = v.y, cc = v.z, d = v.w;
      s  += (a + bb) + (cc + d);
      s2 += (a * a + bb * bb) + (cc * cc + d * d);
    }
    __shared__ double rs[1024], rq[1024];
    rs[tid] = s; rq[tid] = s2; __syncthreads();
    for (int o = 512; o > 0; o >>= 1) {
      if (tid < o) { rs[tid] += rs[tid + o]; rq[tid] += rq[tid + o]; }
      __syncthreads();
    }
    if (tid == 0) {
      double mean = rs[0] / (double)NPIX;
      double var = rq[0] / (double)NPIX - mean * mean;
      stats[c] = mean;
      stats[C + c] = (double)gamma[c] / sqrt(var + 1e-4);
    }
  } else if (b < 320) {
    // weights OIHW -> [co][tap][perm(c)] bf16 (RNE); 4 co per block, coalesced reads
    int co = (b - 256) * 4 + (tid >> 8);
    int c  = tid & 255;
    const float* src = cw + (size_t)co * KTOT + c * 9;
    unsigned short* dst = Wp + (size_t)co * KTOT;
    int p = (c & 31) * 8 + (c >> 5);           // perm slot for channel c
#pragma unroll
    for (int t9 = 0; t9 < 9; ++t9) {
      unsigned u = __builtin_bit_cast(unsigned, src[t9]);
      unsigned lsb = (u >> 16) & 1u;
      u += 0x7FFFu + lsb;
      dst[t9 * 256 + p] = (unsigned short)(u >> 16);
    }
  } else if (b < 434) {
    int g = (b - 320) * 1024 + tid;  // 114*1024 = 116736 = 16*228*32 exactly
    int n = g / 7296; int r = g - n * 7296;
    int pix = r >> 5, c8 = r & 31;
    int h, w;
    if (pix < 58)      { h = 0;  w = pix; }
    else if (pix < 116){ h = 57; w = pix - 58; }
    else { int rem = pix - 116; h = 1 + (rem >> 1); w = (rem & 1) ? 57 : 0; }
    uint4 z = {0u, 0u, 0u, 0u};
    *(uint4*)(Tp + (size_t)((n * PH + h) * PW + w) * C + c8 * 8) = z;
  } else {
    int i = (b - 434) * 1024 + tid;
    if (i < NPIXP) csum[i] = 0.f;
  }
}

// ------- kernel 2: ternarize -> padded NHWC (channel-permuted) bf16 Tp + c_sum -------
__global__ __launch_bounds__(256) void ternarize_kernel(const float* __restrict__ x,
                                 const float* __restrict__ beta,
                                 const double* __restrict__ stats,
                                 unsigned short* __restrict__ Tp, float* __restrict__ csum) {
  int bid = blockIdx.x, tid = threadIdx.x;
  int n = bid / HH, h = bid - n * HH;
  __shared__ float xs[256][57];   // stride 57: transposed reads conflict-free
  const float* xb = x + (size_t)n * CHW + h * WW;
#pragma unroll
  for (int j = 0; j < 14; ++j) {
    int idx = j * 256 + tid;
    int c = idx / 14, q = idx - c * 14;
    float4 v = *(const float4*)(xb + (size_t)c * HW + q * 4);
    float* row = &xs[c][q * 4];
    row[0] = v.x; row[1] = v.y; row[2] = v.z; row[3] = v.w;
  }
  int c8 = tid & 31;
  double mu[8], sc[8], bt[8];
#pragma unroll
  for (int e = 0; e < 8; ++e) {
    int c = c8 + 32 * e;
    mu[e] = stats[c]; sc[e] = stats[C + c]; bt[e] = (double)beta[c];
  }
  __syncthreads();
  unsigned short* tb = Tp + ((size_t)(n * PH + h + 1) * PW + 1) * C;
  float* cs = csum + (size_t)(n * PH + h + 1) * PW + 1;
#pragma unroll
  for (int p = 0; p < 7; ++p) {
    int idx = p * 256 + tid;
    int w = idx >> 5;
    unsigned bits[4];
    float msum = 0.f;
#pragma unroll
    for (int e2 = 0; e2 < 4; ++e2) {
      unsigned lo, hi;
      {
        double xn = ((double)xs[c8 + 64 * e2][w] - mu[2 * e2]) * sc[2 * e2] + bt[2 * e2];
        lo = (xn > 0.0) ? 0x3F80u : 0xBF80u;
        msum += (float)fmin(fabs(xn), 1.0);
      }
      {
        double xn = ((double)xs[c8 + 64 * e2 + 32][w] - mu[2 * e2 + 1]) * sc[2 * e2 + 1] + bt[2 * e2 + 1];
        hi = (xn > 0.0) ? 0x3F80u : 0xBF80u;
        msum += (float)fmin(fabs(xn), 1.0);
      }
      bits[e2] = lo | (hi << 16);
    }
    msum += __shfl_xor(msum, 1); msum += __shfl_xor(msum, 2);
    msum += __shfl_xor(msum, 4); msum += __shfl_xor(msum, 8);
    msum += __shfl_xor(msum, 16);
    uint4 v4; v4.x = bits[0]; v4.y = bits[1]; v4.z = bits[2]; v4.w = bits[3];
    *(uint4*)(tb + (size_t)w * C + c8 * 8) = v4;
    if (c8 == 0) cs[w] = msum;
  }
}

// ------- kernel 3: BM=256 x BN=256 8-wave deep-pipelined ternary conv -------
// 211 blocks (one pixel-tile each) x 512 thr -> every CU holds <=1 block, single
// round, no tail; B window staged ONCE per block (was 4x across co-tiles).
// Waves 2M x 4N: per-wave 128co x 64pix, acc[8][4], 64 MFMA + 24 ds_read_b128
// per K-step (0.375 ratio = the verified 8-phase-template ratio).
// LDS: A dbuf 2x32KB (one tap: [half128co][ks][co][seg], ks-major keeps proven
// 64B-row swizzle) + B dbuf 2x48KB (384-row kh/kw-UNION x 64ch, [ks][row][seg])
// = 163,840 B (160 KiB exactly).
// Schedule per tap-stage (36 total): [sched_bar + s_barrier] -> issue A(t+1)
// 4 GLL [+ B(c+1) 6 GLL at tap==6] -> s_waitcnt vmcnt(4|10) (NEVER 0 in-loop;
// exact per-stage outstanding audit in comments) -> s_barrier -> 2 ks-phases of
// {12 ds_read || setprio(1) 32 MFMA}. Every prefetch has a full compute phase
// (~2.4k cyc) in flight before its wait. No __syncthreads in the loop (its
// hidden vmcnt(0) is the m97-structure drain we are escaping).
__global__ __launch_bounds__(512, 2) void conv_kernel(const unsigned short* __restrict__ Wp,
    const unsigned short* __restrict__ Tp, const float* __restrict__ convb,
    const float* __restrict__ csum, const float* __restrict__ betab,
    float* __restrict__ out) {
  int pt = blockIdx.x;                 // pixel tile 0..210
  int tid = threadIdx.x;

  __shared__ __align__(16) unsigned short Abuf[2][16384];   // 2 x 32,768 B
  __shared__ __align__(16) unsigned short Bbuf[2][24576];   // 2 x 49,152 B

  // ---- A staging plan (per tap): 4 GLL, lin = r*512+tid ->
  //      [half][ks][co127][pseg]; src = Wp + co*KTOT + tap*256 + cc*64 + ks*32 + lseg*8
  int aofs[4];
#pragma unroll
  for (int r = 0; r < 4; ++r) {
    int lin = r * 512 + tid;
    int half = lin >> 10, ks = (lin >> 9) & 1, co127 = (lin >> 2) & 127, pseg = lin & 3;
    int lseg = pseg ^ ((co127 >> 1) & 3);
    aofs[r] = (half * 128 + co127) * KTOT + ks * 32 + lseg * 8;   // + tap*256 + cc*64
  }
  // ---- B staging plan (per c64 chunk): 6 GLL, lin = r*512+tid ->
  //      [ks(r>=3)][row384][pseg]; src = Tp + q*C + cc*64 + ks*32 + lseg*8
  int wstart = pt * 256 - 59;
  int bofs[6];
#pragma unroll
  for (int r = 0; r < 6; ++r) {
    int ks = (r >= 3);
    int row = ((r - ks * 3) * 512 + tid) >> 2;
    int pseg = tid & 3;
    int lseg = pseg ^ ((row >> 1) & 3);
    int q = wstart + row;
    q = q < 0 ? 0 : (q >= NPIXP ? NPIXP - 1 : q);   // clamped rows feed only skipped outputs
    bofs[r] = q * C + ks * 32 + lseg * 8;            // + cc*64
  }

  int lane = tid & 63, wid = tid >> 6;
  int wr = wid >> 2, wc = wid & 3;             // 2M x 4N wave grid
  int quad = lane >> 4, row16 = lane & 15;
  // A read: + mi*512 + ks*4096 (shorts); row stride 64 B, proven swizzle
  int aRd = wr * 8192 + row16 * 32 + (quad ^ ((row16 >> 1) & 3)) * 8;
  int wcr = wc * 64 + row16;                   // B row base (+ ni*16 + kh*58 + kw)

  f32x4 acc[8][4];
#pragma unroll
  for (int mi = 0; mi < 8; ++mi)
#pragma unroll
    for (int ni = 0; ni < 4; ++ni)
      acc[mi][ni] = (f32x4){0.f, 0.f, 0.f, 0.f};

  // prologue: B(cc=0) 6 GLL -> Bbuf0 ; A(tap=0,cc=0) 4 GLL -> Abuf0   [O=10]
  {
    unsigned short* bd = &Bbuf[0][0] + tid * 8;
#pragma unroll
    for (int r = 0; r < 6; ++r) GLL(Tp + bofs[r], bd + r * 4096);
    unsigned short* ad = &Abuf[0][0] + tid * 8;
#pragma unroll
    for (int r = 0; r < 4; ++r) GLL(Wp + aofs[r], ad + r * 4096);
  }

  for (int cc = 0; cc < 4; ++cc) {
    for (int tap = 0; tap < 9; ++tap) {
      int s = cc * 9 + tap;
      // ---- barrier 1: all waves done reading buffers the prefetch will overwrite
      __builtin_amdgcn_sched_barrier(0);
      __builtin_amdgcn_s_barrier();
      __builtin_amdgcn_sched_barrier(0);
      // ---- issue A(s+1)
      if (s < 35) {
        int ntap = (tap == 8) ? 0 : tap + 1;
        int ncc  = (tap == 8) ? cc + 1 : cc;
        int aadd = ntap * 256 + ncc * 64;
        unsigned short* ad = &Abuf[(s + 1) & 1][0] + tid * 8;
#pragma unroll
        for (int r = 0; r < 4; ++r) GLL(Wp + aofs[r] + aadd, ad + r * 4096);
      }
      // ---- issue B(cc+1) once per chunk, 3 stages early
      if (tap == 6 && cc < 3) {
        int badd = (cc + 1) * 64;
        unsigned short* bd = &Bbuf[(cc + 1) & 1][0] + tid * 8;
#pragma unroll
        for (int r = 0; r < 6; ++r) GLL(Tp + bofs[r] + badd, bd + r * 4096);
      }
      // ---- counted waits (audited outstanding: steady 8 -> keep 4;
      //      tap6: 14 -> keep A(t+1)+B = 10; tap7: 14 -> keep B+A(t+1) = 10;
      //      tap8: 14 -> keep A(next) = 4 (retires B in-order, landed);
      //      s=35: 4 -> 0, single final drain)
      if (s == 35)                                 asm volatile("s_waitcnt vmcnt(0)" ::: "memory");
      else if ((tap == 6 || tap == 7) && cc < 3)   asm volatile("s_waitcnt vmcnt(10)" ::: "memory");
      else                                         asm volatile("s_waitcnt vmcnt(4)" ::: "memory");
      __builtin_amdgcn_s_barrier();
      __builtin_amdgcn_sched_barrier(0);
      // ---- compute: 2 ks-phases x {8 A-reads + 4 B-reads, 32 MFMA}
      int kh = tap / 3;
      int rbase = wcr + tap + 55 * kh;             // wcr + kh*58 + kw
      int bsw = (quad ^ ((rbase >> 1) & 3)) * 8;   // invariant across ni (+16) and ks
      const unsigned short* aB = &Abuf[s & 1][0] + aRd;
      const unsigned short* bB = &Bbuf[cc & 1][0] + rbase * 32 + bsw;
#pragma unroll
      for (int ks = 0; ks < 2; ++ks) {
        bf16x8 a[8], b[4];
#pragma unroll
        for (int mi = 0; mi < 8; ++mi)
          a[mi] = *(const bf16x8*)(aB + ks * 4096 + mi * 512);
#pragma unroll
        for (int ni = 0; ni < 4; ++ni)
          b[ni] = *(const bf16x8*)(bB + ks * 12288 + ni * 512);
        __builtin_amdgcn_s_setprio(1);
#pragma unroll
        for (int mi = 0; mi < 8; ++mi)
#pragma unroll
          for (int ni = 0; ni < 4; ++ni)
            acc[mi][ni] = __builtin_amdgcn_mfma_f32_16x16x32_bf16(a[mi], b[ni], acc[mi][ni], 0, 0, 0);
        __builtin_amdgcn_s_setprio(0);
      }
    }
  }

  // epilogue: out = (acc + conv_b) * beta_map(inline) ; skip padded-border outputs
  float bb = betab[0];
#pragma unroll
  for (int ni = 0; ni < 4; ++ni) {
    int pp = pt * 256 + wc * 64 + ni * 16 + row16;
    if (pp >= NPIXP) continue;
    int n = pp / PPI; int r2 = pp - n * PPI;
    int ph = r2 / PW;  int pw = r2 - ph * PW;
    if (ph < 1 || ph > 56 || pw < 1 || pw > 56) continue;
    const float* cp = csum + (size_t)(n * PH + ph - 1) * PW + (pw - 1);
    float s9 = 0.f;
#pragma unroll
    for (int i = 0; i < 3; ++i)
#pragma unroll
      for (int j = 0; j < 3; ++j) s9 += cp[i * PW + j];
    int rows = 3 - (ph == 1) - (ph == 56);
    int cols = 3 - (pw == 1) - (pw == 56);
    float bm = (s9 + bb) / (256.0f * (float)(rows * cols) + bb);
    int pix = (ph - 1) * WW + (pw - 1);
    float* ob = out + (size_t)n * CHW + pix;
#pragma unroll
    for (int mi = 0; mi < 8; ++mi) {
      int co = wr * 128 + mi * 16 + quad * 4;
#pragma unroll
      for (int rg = 0; rg < 4; ++rg) {
        ob[(size_t)(co + rg) * HW] = (acc[mi][ni][rg] + convb[co + rg]) * bm;
      }
    }
  }
}

extern "C" void kernel_launch(void* const* d_in, const int* in_sizes, int n_in,
                              void* d_out, int out_size, void* d_ws, size_t ws_size,
                              hipStream_t stream) {
  const float* x     = (const float*)d_in[0];
  const float* gamma = (const float*)d_in[1];
  const float* beta  = (const float*)d_in[2];
  const float* convw = (const float*)d_in[3];
  const float* convb = (const float*)d_in[4];
  const float* betab = (const float*)d_in[5];
  float* out = (float*)d_out;

  char* ws = (char*)d_ws;
  unsigned short* Tp   = (unsigned short*)(ws);                 // 16*58*58*256*2 = 27,557,888
  unsigned short* Wp   = (unsigned short*)(ws + 27557888);      // 256*2304*2     =  1,179,648
  float*          csum = (float*)(ws + 28737536);               // 16*58*58*4     =    215,296
  double*         stats= (double*)(ws + 29153536);              // 512*8          =      4,096

  prep_stats_kernel<<<487, 1024, 0, stream>>>(x, gamma, convw, stats, Wp, Tp, csum);
  ternarize_kernel<<<896, 256, 0, stream>>>(x, beta, stats, Tp, csum);
  conv_kernel<<<211, 512, 0, stream>>>(Wp, Tp, convb, csum, betab, out);
}